// Round 3
// baseline (343.666 us; speedup 1.0000x reference)
//
#include <hip/hip_runtime.h>
#include <hip/hip_bf16.h>
#include <cstdint>
#include <cstddef>

// out[B,OUT] = (x * alpha) @ W,  W[i,o] = exp(-||col_i - row_o||^2)
// B=8192, IN=4096, OUT=4096.  f32 in/out.
//
// Pipeline:
//   k0: convert x f32 -> bf16 Xb            (d_ws + 32MB, 64 MB)
//   k1: Wt[o][i] = alpha[i]*exp(-d2), bf16  (d_ws, 32 MB)  [B^T layout]
//   k2: 256x256 4-phase/K-tile counted-vmcnt bf16 MFMA GEMM
//
// GEMM schedule (per K-tile BK=64, 4 phases; 2 LDS buffers of 1 K-tile each):
//   LDS layout per buf: A[4 slices][256 rows][16 cols] + B likewise; slice = 16 k's.
//   Stage unit u = {A slice u, B slice u} = 2 gload_lds/thread.
//   Phase q of iter t:  q0: read(kk0 A,n01) stage Kt+1.u2->buf^1
//                       q1: read(kk0 n23)   stage Kt+1.u3->buf^1  vmcnt(6)
//                       q2: read(kk1 A,n01) stage Kt+2.u0->buf
//                       q3: read(kk1 n23)   stage Kt+2.u1->buf    vmcnt(6)
//   Phase body: ds_reads; stage; [vmcnt(6)]; s_barrier; setprio(1); 16 MFMA; setprio(0); s_barrier.
//   NO sched_barrier / blanket lgkmcnt: compiler's dependency-tracked lgkmcnt(k)
//   lets next-phase ds_reads hoist into the MFMA cluster (read/MFMA overlap).
//   vmcnt(6) = 3 units in flight; unit staged at phase X is drain-confirmed by the
//   wait at X+2..X+3, first read at X+6 (>=2 barriers after confirm => cross-wave safe).
//   Swizzle: 16B chunk c holds linear chunk c ^ ((c>>3)&1): fragment reads
//   (16 lanes, rows stride 32B) spread across banks -> 2-way = free.

#define IN_DIM  4096
#define OUT_DIM 4096
#define BATCH   8192

#define BM 256
#define BN 256
#define BK 64
#define KTILES (IN_DIM / BK)   // 64
#define THREADS 512

#define SLICE  4096            // elems per k-slice (256 rows * 16)
#define OPOFF  16384           // A -> B offset (4 slices)
#define BUFOFF 32768           // elems per buffer (A + B)

typedef __bf16 bf16x8 __attribute__((ext_vector_type(8)));
typedef float  f32x4  __attribute__((ext_vector_type(4)));

// ---------------------------------------------------------------------------
__global__ __launch_bounds__(256) void convert_x_kernel(
    const float* __restrict__ x, __bf16* __restrict__ xb)
{
    const size_t i = ((size_t)blockIdx.x * 256 + threadIdx.x) * 8;
    const float4 v0 = *(const float4*)(x + i);
    const float4 v1 = *(const float4*)(x + i + 4);
    bf16x8 o;
    o[0] = (__bf16)v0.x; o[1] = (__bf16)v0.y; o[2] = (__bf16)v0.z; o[3] = (__bf16)v0.w;
    o[4] = (__bf16)v1.x; o[5] = (__bf16)v1.y; o[6] = (__bf16)v1.z; o[7] = (__bf16)v1.w;
    *(bf16x8*)(xb + i) = o;
}

// ---------------------------------------------------------------------------
__global__ __launch_bounds__(256) void build_wt_kernel(
    const float* __restrict__ rows_mean,     // [OUT,2]
    const float* __restrict__ columns_mean,  // [IN,2]
    const float* __restrict__ alpha,         // [IN]
    __bf16* __restrict__ Wt)                 // [OUT][IN]
{
    const int o  = blockIdx.y;
    const int i0 = (blockIdx.x * 256 + threadIdx.x) * 8;

    const float r0 = rows_mean[2 * o];
    const float r1 = rows_mean[2 * o + 1];

    const float4* cm = (const float4*)(columns_mean + 2 * (size_t)i0);
    float4 c01 = cm[0], c23 = cm[1], c45 = cm[2], c67 = cm[3];
    const float4* ap = (const float4*)(alpha + i0);
    float4 a0 = ap[0], a1 = ap[1];

    float cx[8] = {c01.x, c01.z, c23.x, c23.z, c45.x, c45.z, c67.x, c67.z};
    float cy[8] = {c01.y, c01.w, c23.y, c23.w, c45.y, c45.w, c67.y, c67.w};
    float av[8] = {a0.x, a0.y, a0.z, a0.w, a1.x, a1.y, a1.z, a1.w};

    bf16x8 w;
#pragma unroll
    for (int j = 0; j < 8; ++j) {
        float d0 = cx[j] - r0;
        float d1 = cy[j] - r1;
        w[j] = (__bf16)(__expf(-(d0 * d0 + d1 * d1)) * av[j]);
    }
    *(bf16x8*)(Wt + (size_t)o * IN_DIM + i0) = w;
}

// ---------------------------------------------------------------------------
__global__ __launch_bounds__(THREADS, 2) void gemm_kernel(
    const __bf16* __restrict__ Xb,   // [BATCH, IN] bf16
    const __bf16* __restrict__ Wt,   // [OUT][IN]   bf16 (B^T)
    float* __restrict__ Out)         // [BATCH, OUT]
{
    __shared__ __align__(16) __bf16 lds[2 * BUFOFF];   // 128 KiB

    const int tid  = threadIdx.x;
    const int wave = tid >> 6;
    const int lane = tid & 63;
    const int lh   = lane >> 4;          // 0..3
    const int lr   = lane & 15;
    const int wm   = wave >> 2;          // 0..1  (M waves)
    const int wn   = wave & 3;           // 0..3  (N waves)

    // ---- XCD-aware block swizzle (512 wg, 512%8==0 -> simple bijection) ----
    const int nwg  = (BATCH / BM) * (OUT_DIM / BN);          // 512
    const int swz  = (blockIdx.x & 7) * (nwg >> 3) + (blockIdx.x >> 3);
    const int m0   = (swz >> 4) * BM;                        // 32 m-tiles
    const int n0   = (swz & 15) * BN;                        // 16 n-tiles

    // ---- staging addresses (pre-swizzled global source, linear LDS dest) ----
    const int g    = tid ^ ((tid >> 3) & 1);   // swizzled 16B chunk id
    const int grow = g >> 1;                   // 0..255
    const int gc8  = (g & 1) * 8;
    const __bf16* gA = Xb + (size_t)(m0 + grow) * IN_DIM + gc8;
    const __bf16* gB = Wt + (size_t)(n0 + grow) * IN_DIM + gc8;
    __bf16* sA = lds + wave * 512;             // wave-uniform LDS dest bases
    __bf16* sB = lds + OPOFF + wave * 512;

    auto STAGE = [&](int kt, int u, int b) {
        const __bf16* ga = gA + (size_t)kt * BK + u * 16;
        const __bf16* gb = gB + (size_t)kt * BK + u * 16;
        __builtin_amdgcn_global_load_lds(
            (const __attribute__((address_space(1))) unsigned int*)ga,
            (__attribute__((address_space(3))) unsigned int*)(sA + b * BUFOFF + u * SLICE),
            16, 0, 0);
        __builtin_amdgcn_global_load_lds(
            (const __attribute__((address_space(1))) unsigned int*)gb,
            (__attribute__((address_space(3))) unsigned int*)(sB + b * BUFOFF + u * SLICE),
            16, 0, 0);
    };

    // ---- fragment read bases (swizzled) ----
    const int c8x = ((lh & 1) * 8) ^ (((lr >> 2) & 1) << 3);
    const __bf16* aRd = lds + (lh >> 1) * SLICE + (wm * 128 + lr) * 16 + c8x;
    const __bf16* bRd = lds + OPOFF + (lh >> 1) * SLICE + (wn * 64 + lr) * 16 + c8x;

    f32x4 acc[8][4];
#pragma unroll
    for (int m = 0; m < 8; ++m)
#pragma unroll
        for (int n = 0; n < 4; ++n)
            acc[m][n] = f32x4{0.f, 0.f, 0.f, 0.f};

    // ---- prologue: K0 all units -> buf0, K1 u0,u1 -> buf1 ----
    STAGE(0, 0, 0); STAGE(0, 1, 0); STAGE(0, 2, 0); STAGE(0, 3, 0);
    STAGE(1, 0, 1); STAGE(1, 1, 1);
    asm volatile("s_waitcnt vmcnt(4)" ::: "memory");
    __builtin_amdgcn_s_barrier();

    bf16x8 af[8];

    for (int t = 0; t < KTILES; ++t) {
        const int buf = t & 1;
        const int bo  = buf * BUFOFF;
        const int kt1 = (t + 1 < KTILES) ? t + 1 : KTILES - 1;  // clamped (benign)
        const int kt2 = (t + 2 < KTILES) ? t + 2 : KTILES - 1;

        // ================= phase 0: kk=0, n={0,1} =================
        {
#pragma unroll
            for (int m = 0; m < 8; ++m)
                af[m] = *(const bf16x8*)(aRd + bo + m * 256);
            bf16x8 b0 = *(const bf16x8*)(bRd + bo + 0 * 256);
            bf16x8 b1 = *(const bf16x8*)(bRd + bo + 1 * 256);
            STAGE(kt1, 2, buf ^ 1);
            __builtin_amdgcn_s_barrier();
            __builtin_amdgcn_s_setprio(1);
#pragma unroll
            for (int m = 0; m < 8; ++m) {
                acc[m][0] = __builtin_amdgcn_mfma_f32_16x16x32_bf16(af[m], b0, acc[m][0], 0, 0, 0);
                acc[m][1] = __builtin_amdgcn_mfma_f32_16x16x32_bf16(af[m], b1, acc[m][1], 0, 0, 0);
            }
            __builtin_amdgcn_s_setprio(0);
            __builtin_amdgcn_s_barrier();
        }
        // ================= phase 1: kk=0, n={2,3} =================
        {
            bf16x8 b2 = *(const bf16x8*)(bRd + bo + 2 * 256);
            bf16x8 b3 = *(const bf16x8*)(bRd + bo + 3 * 256);
            STAGE(kt1, 3, buf ^ 1);
            asm volatile("s_waitcnt vmcnt(6)" ::: "memory");
            __builtin_amdgcn_s_barrier();
            __builtin_amdgcn_s_setprio(1);
#pragma unroll
            for (int m = 0; m < 8; ++m) {
                acc[m][2] = __builtin_amdgcn_mfma_f32_16x16x32_bf16(af[m], b2, acc[m][2], 0, 0, 0);
                acc[m][3] = __builtin_amdgcn_mfma_f32_16x16x32_bf16(af[m], b3, acc[m][3], 0, 0, 0);
            }
            __builtin_amdgcn_s_setprio(0);
            __builtin_amdgcn_s_barrier();
        }
        // ================= phase 2: kk=1, n={0,1} =================
        {
#pragma unroll
            for (int m = 0; m < 8; ++m)
                af[m] = *(const bf16x8*)(aRd + bo + 2 * SLICE + m * 256);
            bf16x8 b0 = *(const bf16x8*)(bRd + bo + 2 * SLICE + 0 * 256);
            bf16x8 b1 = *(const bf16x8*)(bRd + bo + 2 * SLICE + 1 * 256);
            STAGE(kt2, 0, buf);
            __builtin_amdgcn_s_barrier();
            __builtin_amdgcn_s_setprio(1);
#pragma unroll
            for (int m = 0; m < 8; ++m) {
                acc[m][0] = __builtin_amdgcn_mfma_f32_16x16x32_bf16(af[m], b0, acc[m][0], 0, 0, 0);
                acc[m][1] = __builtin_amdgcn_mfma_f32_16x16x32_bf16(af[m], b1, acc[m][1], 0, 0, 0);
            }
            __builtin_amdgcn_s_setprio(0);
            __builtin_amdgcn_s_barrier();
        }
        // ================= phase 3: kk=1, n={2,3} =================
        {
            bf16x8 b2 = *(const bf16x8*)(bRd + bo + 2 * SLICE + 2 * 256);
            bf16x8 b3 = *(const bf16x8*)(bRd + bo + 2 * SLICE + 3 * 256);
            STAGE(kt2, 1, buf);
            asm volatile("s_waitcnt vmcnt(6)" ::: "memory");
            __builtin_amdgcn_s_barrier();
            __builtin_amdgcn_s_setprio(1);
#pragma unroll
            for (int m = 0; m < 8; ++m) {
                acc[m][2] = __builtin_amdgcn_mfma_f32_16x16x32_bf16(af[m], b2, acc[m][2], 0, 0, 0);
                acc[m][3] = __builtin_amdgcn_mfma_f32_16x16x32_bf16(af[m], b3, acc[m][3], 0, 0, 0);
            }
            __builtin_amdgcn_s_setprio(0);
            __builtin_amdgcn_s_barrier();
        }
    }

    // ---- epilogue: C/D layout col=lane&15, row=(lane>>4)*4+j ----
    const int crow = m0 + wm * 128 + lh * 4;
    const int ccol = n0 + wn * 64 + lr;
#pragma unroll
    for (int m = 0; m < 8; ++m)
#pragma unroll
        for (int n = 0; n < 4; ++n) {
            float* o = Out + (size_t)(crow + m * 16) * OUT_DIM + (ccol + n * 16);
#pragma unroll
            for (int j = 0; j < 4; ++j)
                o[(size_t)j * OUT_DIM] = acc[m][n][j];
        }
}

// ---------------------------------------------------------------------------
extern "C" void kernel_launch(void* const* d_in, const int* in_sizes, int n_in,
                              void* d_out, int out_size, void* d_ws, size_t ws_size,
                              hipStream_t stream) {
    const float* x  = (const float*)d_in[0];   // [8192, 4096]
    const float* rm = (const float*)d_in[1];   // [4096, 2]
    const float* cm = (const float*)d_in[2];   // [4096, 2]
    const float* al = (const float*)d_in[3];   // [4096]
    float* out = (float*)d_out;                // [8192, 4096]

    __bf16* Wt = (__bf16*)d_ws;                                     // 32 MiB
    __bf16* Xb = (__bf16*)((char*)d_ws + (size_t)32 * 1024 * 1024); // 64 MiB

    convert_x_kernel<<<BATCH * IN_DIM / (256 * 8), 256, 0, stream>>>(x, Xb);

    dim3 g1(IN_DIM / (256 * 8), OUT_DIM);      // (2, 4096)
    build_wt_kernel<<<g1, 256, 0, stream>>>(rm, cm, al, Wt);

    dim3 g2((BATCH / BM) * (OUT_DIM / BN));    // 512
    gemm_kernel<<<g2, THREADS, 0, stream>>>(Xb, Wt, out);
}

// Round 4
// 317.164 us; speedup vs baseline: 1.0836x; 1.0836x over previous
//
#include <hip/hip_runtime.h>
#include <hip/hip_bf16.h>
#include <cstdint>
#include <cstddef>

// out[B,OUT] = (x * alpha) @ W,  W[i,o] = exp(-||col_i - row_o||^2)
// B=8192, IN=4096, OUT=4096.  f32 in/out.
//
// Pipeline:
//   k0: convert x f32 -> bf16 Xb            (d_ws + 32MB, 64 MB)
//   k1: Wt[o][i] = alpha[i]*exp(-d2), bf16  (d_ws, 32 MB)  [B^T layout]
//   k2: 256x256 2-phase/K-tile counted-vmcnt bf16 MFMA GEMM
//
// GEMM schedule (BK=64, 2 phases per K-tile = ksub0/ksub1; 2 LDS buffers):
//   LDS per buf: A[4 slices][256 rows][16 cols] + B likewise; slice = 16 k's.
//   Stage unit u = {A slice u, B slice u} = 2 gload_lds/thread.
//   Phase A of tile t: read b0..b3 THEN af0..af7 (ksub0); stage u0,u1(t+1)->buf^1;
//                      vmcnt(4); barrier; 32 MFMA (m-major); barrier.
//   Phase B: same for ksub1; stage u2,u3(t+1); vmcnt(4).
//   READ ORDER MATTERS: B-frags first so the first MFMA (af0*b0) waits for only
//   3 reads, and each arriving af[m] unlocks 4 MFMAs -> LDS drain streams under
//   the MFMA pipe instead of convoy-serializing (the round-3 36% MfmaUtil bug).
//   vmcnt(4) confirms the prior phase's staged unit-pair; u01(t+1) staged @A(t),
//   confirmed @B(t)'s vmcnt+barrier, first read @A(t+1)  (RAW ok). Slots being
//   staged were last read 2 phases earlier, readers drained by the interleaving
//   barrier (WAR ok). Never drains below 4 loads in flight.
//   Swizzle: 16B chunk c holds linear chunk c ^ ((c>>3)&1): fragment reads
//   conflict-free (measured 0).

#define IN_DIM  4096
#define OUT_DIM 4096
#define BATCH   8192

#define BM 256
#define BN 256
#define BK 64
#define KTILES (IN_DIM / BK)   // 64
#define THREADS 512

#define SLICE  4096            // elems per k-slice (256 rows * 16)
#define OPOFF  16384           // A -> B offset (4 slices)
#define BUFOFF 32768           // elems per buffer (A + B)

typedef __bf16 bf16x8 __attribute__((ext_vector_type(8)));
typedef float  f32x4  __attribute__((ext_vector_type(4)));

// ---------------------------------------------------------------------------
__global__ __launch_bounds__(256) void convert_x_kernel(
    const float* __restrict__ x, __bf16* __restrict__ xb)
{
    const size_t i = ((size_t)blockIdx.x * 256 + threadIdx.x) * 8;
    const float4 v0 = *(const float4*)(x + i);
    const float4 v1 = *(const float4*)(x + i + 4);
    bf16x8 o;
    o[0] = (__bf16)v0.x; o[1] = (__bf16)v0.y; o[2] = (__bf16)v0.z; o[3] = (__bf16)v0.w;
    o[4] = (__bf16)v1.x; o[5] = (__bf16)v1.y; o[6] = (__bf16)v1.z; o[7] = (__bf16)v1.w;
    *(bf16x8*)(xb + i) = o;
}

// ---------------------------------------------------------------------------
__global__ __launch_bounds__(256) void build_wt_kernel(
    const float* __restrict__ rows_mean,     // [OUT,2]
    const float* __restrict__ columns_mean,  // [IN,2]
    const float* __restrict__ alpha,         // [IN]
    __bf16* __restrict__ Wt)                 // [OUT][IN]
{
    const int o  = blockIdx.y;
    const int i0 = (blockIdx.x * 256 + threadIdx.x) * 8;

    const float r0 = rows_mean[2 * o];
    const float r1 = rows_mean[2 * o + 1];

    const float4* cm = (const float4*)(columns_mean + 2 * (size_t)i0);
    float4 c01 = cm[0], c23 = cm[1], c45 = cm[2], c67 = cm[3];
    const float4* ap = (const float4*)(alpha + i0);
    float4 a0 = ap[0], a1 = ap[1];

    float cx[8] = {c01.x, c01.z, c23.x, c23.z, c45.x, c45.z, c67.x, c67.z};
    float cy[8] = {c01.y, c01.w, c23.y, c23.w, c45.y, c45.w, c67.y, c67.w};
    float av[8] = {a0.x, a0.y, a0.z, a0.w, a1.x, a1.y, a1.z, a1.w};

    bf16x8 w;
#pragma unroll
    for (int j = 0; j < 8; ++j) {
        float d0 = cx[j] - r0;
        float d1 = cy[j] - r1;
        w[j] = (__bf16)(__expf(-(d0 * d0 + d1 * d1)) * av[j]);
    }
    *(bf16x8*)(Wt + (size_t)o * IN_DIM + i0) = w;
}

// ---------------------------------------------------------------------------
__global__ __launch_bounds__(THREADS, 2) void gemm_kernel(
    const __bf16* __restrict__ Xb,   // [BATCH, IN] bf16
    const __bf16* __restrict__ Wt,   // [OUT][IN]   bf16 (B^T)
    float* __restrict__ Out)         // [BATCH, OUT]
{
    __shared__ __align__(16) __bf16 lds[2 * BUFOFF];   // 128 KiB

    const int tid  = threadIdx.x;
    const int wave = tid >> 6;
    const int lane = tid & 63;
    const int lh   = lane >> 4;          // 0..3
    const int lr   = lane & 15;
    const int wm   = wave >> 2;          // 0..1  (M waves)
    const int wn   = wave & 3;           // 0..3  (N waves)

    // ---- XCD-aware block swizzle (512 wg, 512%8==0 -> simple bijection) ----
    const int nwg  = (BATCH / BM) * (OUT_DIM / BN);          // 512
    const int swz  = (blockIdx.x & 7) * (nwg >> 3) + (blockIdx.x >> 3);
    const int m0   = (swz >> 4) * BM;                        // 32 m-tiles
    const int n0   = (swz & 15) * BN;                        // 16 n-tiles

    // ---- staging addresses (pre-swizzled global source, linear LDS dest) ----
    const int g    = tid ^ ((tid >> 3) & 1);   // swizzled 16B chunk id
    const int grow = g >> 1;                   // 0..255
    const int gc8  = (g & 1) * 8;
    const __bf16* gA = Xb + (size_t)(m0 + grow) * IN_DIM + gc8;
    const __bf16* gB = Wt + (size_t)(n0 + grow) * IN_DIM + gc8;
    __bf16* sA = lds + wave * 512;             // wave-uniform LDS dest bases
    __bf16* sB = lds + OPOFF + wave * 512;

    auto STAGE = [&](int kt, int u, int b) {
        const __bf16* ga = gA + (size_t)kt * BK + u * 16;
        const __bf16* gb = gB + (size_t)kt * BK + u * 16;
        __builtin_amdgcn_global_load_lds(
            (const __attribute__((address_space(1))) unsigned int*)ga,
            (__attribute__((address_space(3))) unsigned int*)(sA + b * BUFOFF + u * SLICE),
            16, 0, 0);
        __builtin_amdgcn_global_load_lds(
            (const __attribute__((address_space(1))) unsigned int*)gb,
            (__attribute__((address_space(3))) unsigned int*)(sB + b * BUFOFF + u * SLICE),
            16, 0, 0);
    };

    // ---- fragment read bases (swizzled) ----
    const int c8x = ((lh & 1) * 8) ^ (((lr >> 2) & 1) << 3);
    const __bf16* aRd = lds + (lh >> 1) * SLICE + (wm * 128 + lr) * 16 + c8x;
    const __bf16* bRd = lds + OPOFF + (lh >> 1) * SLICE + (wn * 64 + lr) * 16 + c8x;

    f32x4 acc[8][4];
#pragma unroll
    for (int m = 0; m < 8; ++m)
#pragma unroll
        for (int n = 0; n < 4; ++n)
            acc[m][n] = f32x4{0.f, 0.f, 0.f, 0.f};

    // ---- prologue: K0 all units -> buf0 ----
    STAGE(0, 0, 0); STAGE(0, 1, 0); STAGE(0, 2, 0); STAGE(0, 3, 0);
    asm volatile("s_waitcnt vmcnt(0)" ::: "memory");
    __builtin_amdgcn_s_barrier();

    for (int t = 0; t < KTILES; ++t) {
        const int buf = t & 1;
        const int bo  = buf * BUFOFF;
        const int kt1 = (t + 1 < KTILES) ? t + 1 : KTILES - 1;  // clamped (benign)

        // ============ phase A: ksub0 (slices 0,1), all n ============
        {
            // B first: first MFMA needs only reads {b0, af0}; af[m] stream-unlocks
            bf16x8 b0 = *(const bf16x8*)(bRd + bo + 0 * 256);
            bf16x8 b1 = *(const bf16x8*)(bRd + bo + 1 * 256);
            bf16x8 b2 = *(const bf16x8*)(bRd + bo + 2 * 256);
            bf16x8 b3 = *(const bf16x8*)(bRd + bo + 3 * 256);
            bf16x8 af[8];
#pragma unroll
            for (int m = 0; m < 8; ++m)
                af[m] = *(const bf16x8*)(aRd + bo + m * 256);
            STAGE(kt1, 0, buf ^ 1);
            STAGE(kt1, 1, buf ^ 1);
            asm volatile("s_waitcnt vmcnt(4)" ::: "memory");
            __builtin_amdgcn_s_barrier();
            __builtin_amdgcn_s_setprio(1);
#pragma unroll
            for (int m = 0; m < 8; ++m) {
                acc[m][0] = __builtin_amdgcn_mfma_f32_16x16x32_bf16(af[m], b0, acc[m][0], 0, 0, 0);
                acc[m][1] = __builtin_amdgcn_mfma_f32_16x16x32_bf16(af[m], b1, acc[m][1], 0, 0, 0);
                acc[m][2] = __builtin_amdgcn_mfma_f32_16x16x32_bf16(af[m], b2, acc[m][2], 0, 0, 0);
                acc[m][3] = __builtin_amdgcn_mfma_f32_16x16x32_bf16(af[m], b3, acc[m][3], 0, 0, 0);
            }
            __builtin_amdgcn_s_setprio(0);
            __builtin_amdgcn_s_barrier();
        }
        // ============ phase B: ksub1 (slices 2,3), all n ============
        {
            bf16x8 b0 = *(const bf16x8*)(bRd + bo + 2 * SLICE + 0 * 256);
            bf16x8 b1 = *(const bf16x8*)(bRd + bo + 2 * SLICE + 1 * 256);
            bf16x8 b2 = *(const bf16x8*)(bRd + bo + 2 * SLICE + 2 * 256);
            bf16x8 b3 = *(const bf16x8*)(bRd + bo + 2 * SLICE + 3 * 256);
            bf16x8 af[8];
#pragma unroll
            for (int m = 0; m < 8; ++m)
                af[m] = *(const bf16x8*)(aRd + bo + 2 * SLICE + m * 256);
            STAGE(kt1, 2, buf ^ 1);
            STAGE(kt1, 3, buf ^ 1);
            asm volatile("s_waitcnt vmcnt(4)" ::: "memory");
            __builtin_amdgcn_s_barrier();
            __builtin_amdgcn_s_setprio(1);
#pragma unroll
            for (int m = 0; m < 8; ++m) {
                acc[m][0] = __builtin_amdgcn_mfma_f32_16x16x32_bf16(af[m], b0, acc[m][0], 0, 0, 0);
                acc[m][1] = __builtin_amdgcn_mfma_f32_16x16x32_bf16(af[m], b1, acc[m][1], 0, 0, 0);
                acc[m][2] = __builtin_amdgcn_mfma_f32_16x16x32_bf16(af[m], b2, acc[m][2], 0, 0, 0);
                acc[m][3] = __builtin_amdgcn_mfma_f32_16x16x32_bf16(af[m], b3, acc[m][3], 0, 0, 0);
            }
            __builtin_amdgcn_s_setprio(0);
            __builtin_amdgcn_s_barrier();
        }
    }

    // ---- epilogue: C/D layout col=lane&15, row=(lane>>4)*4+j ----
    const int crow = m0 + wm * 128 + lh * 4;
    const int ccol = n0 + wn * 64 + lr;
#pragma unroll
    for (int m = 0; m < 8; ++m)
#pragma unroll
        for (int n = 0; n < 4; ++n) {
            float* o = Out + (size_t)(crow + m * 16) * OUT_DIM + (ccol + n * 16);
#pragma unroll
            for (int j = 0; j < 4; ++j)
                o[(size_t)j * OUT_DIM] = acc[m][n][j];
        }
}

// ---------------------------------------------------------------------------
extern "C" void kernel_launch(void* const* d_in, const int* in_sizes, int n_in,
                              void* d_out, int out_size, void* d_ws, size_t ws_size,
                              hipStream_t stream) {
    const float* x  = (const float*)d_in[0];   // [8192, 4096]
    const float* rm = (const float*)d_in[1];   // [4096, 2]
    const float* cm = (const float*)d_in[2];   // [4096, 2]
    const float* al = (const float*)d_in[3];   // [4096]
    float* out = (float*)d_out;                // [8192, 4096]

    __bf16* Wt = (__bf16*)d_ws;                                     // 32 MiB
    __bf16* Xb = (__bf16*)((char*)d_ws + (size_t)32 * 1024 * 1024); // 64 MiB

    convert_x_kernel<<<BATCH * IN_DIM / (256 * 8), 256, 0, stream>>>(x, Xb);

    dim3 g1(IN_DIM / (256 * 8), OUT_DIM);      // (2, 4096)
    build_wt_kernel<<<g1, 256, 0, stream>>>(rm, cm, al, Wt);

    dim3 g2((BATCH / BM) * (OUT_DIM / BN));    // 512
    gemm_kernel<<<g2, THREADS, 0, stream>>>(Xb, Wt, out);
}

// Round 5
// 268.950 us; speedup vs baseline: 1.2778x; 1.1793x over previous
//
#include <hip/hip_runtime.h>
#include <hip/hip_bf16.h>
#include <cstdint>
#include <cstddef>

// out[B,OUT] = (x * alpha) @ W,  W[i,o] = exp(-||col_i - row_o||^2)
// B=8192, IN=4096, OUT=4096.  f32 in/out.
//
// k0: x f32 -> bf16 Xb; k1: Wt[o][i] = alpha[i]*exp(-d2) bf16 (B^T); k2: GEMM.
//
// GEMM: 256x256 tile, BK=64, 8 waves (2M x 4N), per-wave C = 128x64.
// 4 quadrant-phases per K-tile: (mq,nq) x full K=64 = 16 MFMA/phase.
// Phase: STAGE(1 unit); vmcnt(6); s_barrier; sched_barrier; ds_reads; MFMA.
// Reads AFTER the barrier: fine-grained lgkmcnt gates each MFMA, so phase p's
// LDS drain overlaps phase p-1's MFMA pipe drain (kills the 2-window serialization
// that capped rounds 1-4 at 36-40% MfmaUtil).
// Stage units = row-strips ([unit][128 rows][64 k]), order A0,B0,B1,A1 during
// tile t for t+1; vmcnt(6) each phase confirms the 3-phase-old unit:
//   A0: staged p0(t), confirmed p3(t), read p0(t+1)   (af lo)
//   B0: staged p1(t), confirmed p0(t+1), read p0(t+1) (bL)
//   B1: staged p2(t), confirmed p1(t+1), read p1(t+1) (bH)
//   A1: staged p3(t), confirmed p2(t+1), read p2(t+1) (af hi)
// WAR: each unit's last ds_read is >=3 barriers before its overwrite.  Never
// drains below 6 in flight.  LDS row permutation: A rho = mq*128+wm*64+i,
// B rho = nq*128+wn*32+j (so each unit is read in exactly one phase).
// Swizzle: 16B chunk kc of row rho stored at kc ^ (rho&7); staging pre-swizzles
// the per-lane GLOBAL address (LDS dest stays linear per gload_lds rules);
// fragment reads: 16-lane groups spread 8 slots x 2 lanes -> conflict-free.

#define IN_DIM  4096
#define OUT_DIM 4096
#define BATCH   8192

#define BM 256
#define BN 256
#define BK 64
#define KTILES (IN_DIM / BK)   // 64
#define THREADS 512

#define UNIT   8192            // elems per stage unit (128 rows * 64)
#define OPOFF  16384           // A (2 units) -> B offset
#define BUFOFF 32768           // elems per buffer (A + B)

typedef __bf16 bf16x8 __attribute__((ext_vector_type(8)));
typedef float  f32x4  __attribute__((ext_vector_type(4)));

// ---------------------------------------------------------------------------
__global__ __launch_bounds__(256) void convert_x_kernel(
    const float* __restrict__ x, __bf16* __restrict__ xb)
{
    const size_t i = ((size_t)blockIdx.x * 256 + threadIdx.x) * 8;
    const float4 v0 = *(const float4*)(x + i);
    const float4 v1 = *(const float4*)(x + i + 4);
    bf16x8 o;
    o[0] = (__bf16)v0.x; o[1] = (__bf16)v0.y; o[2] = (__bf16)v0.z; o[3] = (__bf16)v0.w;
    o[4] = (__bf16)v1.x; o[5] = (__bf16)v1.y; o[6] = (__bf16)v1.z; o[7] = (__bf16)v1.w;
    *(bf16x8*)(xb + i) = o;
}

// ---------------------------------------------------------------------------
__global__ __launch_bounds__(256) void build_wt_kernel(
    const float* __restrict__ rows_mean,     // [OUT,2]
    const float* __restrict__ columns_mean,  // [IN,2]
    const float* __restrict__ alpha,         // [IN]
    __bf16* __restrict__ Wt)                 // [OUT][IN]
{
    const int o  = blockIdx.y;
    const int i0 = (blockIdx.x * 256 + threadIdx.x) * 8;

    const float r0 = rows_mean[2 * o];
    const float r1 = rows_mean[2 * o + 1];

    const float4* cm = (const float4*)(columns_mean + 2 * (size_t)i0);
    float4 c01 = cm[0], c23 = cm[1], c45 = cm[2], c67 = cm[3];
    const float4* ap = (const float4*)(alpha + i0);
    float4 a0 = ap[0], a1 = ap[1];

    float cx[8] = {c01.x, c01.z, c23.x, c23.z, c45.x, c45.z, c67.x, c67.z};
    float cy[8] = {c01.y, c01.w, c23.y, c23.w, c45.y, c45.w, c67.y, c67.w};
    float av[8] = {a0.x, a0.y, a0.z, a0.w, a1.x, a1.y, a1.z, a1.w};

    bf16x8 w;
#pragma unroll
    for (int j = 0; j < 8; ++j) {
        float d0 = cx[j] - r0;
        float d1 = cy[j] - r1;
        w[j] = (__bf16)(__expf(-(d0 * d0 + d1 * d1)) * av[j]);
    }
    *(bf16x8*)(Wt + (size_t)o * IN_DIM + i0) = w;
}

// ---------------------------------------------------------------------------
__global__ __launch_bounds__(THREADS, 2) void gemm_kernel(
    const __bf16* __restrict__ Xb,   // [BATCH, IN] bf16
    const __bf16* __restrict__ Wt,   // [OUT][IN]   bf16 (B^T)
    float* __restrict__ Out)         // [BATCH, OUT]
{
    __shared__ __align__(16) __bf16 lds[2 * BUFOFF];   // 128 KiB

    const int tid  = threadIdx.x;
    const int wave = tid >> 6;
    const int lane = tid & 63;
    const int lh   = lane >> 4;          // 0..3
    const int lr   = lane & 15;
    const int wm   = wave >> 2;          // 0..1  (M waves)
    const int wn   = wave & 3;           // 0..3  (N waves)

    // ---- XCD-aware block swizzle (512 wg, 512%8==0) ----
    const int swz  = (blockIdx.x & 7) * 64 + (blockIdx.x >> 3);
    const int m0   = (swz >> 4) * BM;
    const int n0   = (swz & 15) * BN;

    // ---- staging precompute (2 loads/thread per unit) ----
    // chunk c = wave*64+lane + j*512; rho' = c>>3; k = c&7; kg = k ^ (rho'&7)
    // A global row = (rho'>>6)*128 + (rho'&63) [+ h*64]
    // B global row = (rho'>>5)*64  + (rho'&31) [+ h*32]
    const __bf16 *pA[2], *pB[2];
    __bf16 *lA[2], *lB[2];
#pragma unroll
    for (int j = 0; j < 2; ++j) {
        const int c  = wave * 64 + lane + j * 512;
        const int rp = c >> 3;
        const int kg = (c & 7) ^ (rp & 7);
        const int rA = ((rp >> 6) & 1) * 128 + (rp & 63);
        const int rB = (rp >> 5) * 64 + (rp & 31);
        pA[j] = Xb + (size_t)(m0 + rA) * IN_DIM + kg * 8;
        pB[j] = Wt + (size_t)(n0 + rB) * IN_DIM + kg * 8;
        lA[j] = lds + j * 4096 + wave * 512;          // wave-uniform dest
        lB[j] = lds + OPOFF + j * 4096 + wave * 512;
    }

    auto STAGE_A = [&](int kt, int h, int b) {
#pragma unroll
        for (int j = 0; j < 2; ++j)
            __builtin_amdgcn_global_load_lds(
                (const __attribute__((address_space(1))) unsigned int*)
                    (pA[j] + (size_t)h * 64 * IN_DIM + kt * BK),
                (__attribute__((address_space(3))) unsigned int*)
                    (lA[j] + b * BUFOFF + h * UNIT), 16, 0, 0);
    };
    auto STAGE_B = [&](int kt, int h, int b) {
#pragma unroll
        for (int j = 0; j < 2; ++j)
            __builtin_amdgcn_global_load_lds(
                (const __attribute__((address_space(1))) unsigned int*)
                    (pB[j] + (size_t)h * 32 * IN_DIM + kt * BK),
                (__attribute__((address_space(3))) unsigned int*)
                    (lB[j] + b * BUFOFF + h * UNIT), 16, 0, 0);
    };

    // ---- fragment read bases (swizzled chunks; rho&7 == lr&7) ----
    const int l7  = lr & 7;
    const int sc0 = lh ^ l7;          // kk=0 chunk
    const int sc1 = (4 + lh) ^ l7;    // kk=1 chunk
    const __bf16* aB = lds + (wm * 64 + lr) * 64;
    const __bf16* bB = lds + OPOFF + (wn * 32 + lr) * 64;

    // A frag (m 0..7, kk): rho = (m>>2)*128 + wm*64 + (m&3)*16 + lr
    auto RD_A = [&](int m, int kk, int bo) -> bf16x8 {
        return *(const bf16x8*)(aB + bo + (m >> 2) * UNIT + (m & 3) * 1024
                                + (kk ? sc1 : sc0) * 8);
    };
    // B frag (n 0..3, kk): rho = (n>>1)*128 + wn*32 + (n&1)*16 + lr
    auto RD_B = [&](int n, int kk, int bo) -> bf16x8 {
        return *(const bf16x8*)(bB + bo + (n >> 1) * UNIT + (n & 1) * 1024
                                + (kk ? sc1 : sc0) * 8);
    };

    f32x4 acc[8][4];
#pragma unroll
    for (int m = 0; m < 8; ++m)
#pragma unroll
        for (int n = 0; n < 4; ++n)
            acc[m][n] = f32x4{0.f, 0.f, 0.f, 0.f};

    // ---- prologue: tile 0, all 4 units -> buf0 ----
    STAGE_A(0, 0, 0); STAGE_B(0, 0, 0); STAGE_B(0, 1, 0); STAGE_A(0, 1, 0);
    asm volatile("s_waitcnt vmcnt(0)" ::: "memory");
    __builtin_amdgcn_s_barrier();

    bf16x8 af[4][2], bL[4], bH[4];

    for (int t = 0; t < KTILES; ++t) {
        const int bo  = (t & 1) * BUFOFF;
        const int sb  = (t & 1) ^ 1;
        const int kt1 = (t + 1 < KTILES) ? t + 1 : KTILES - 1;  // clamp benign

        // ===== phase 0: quadrant (mq0, nq0) =====
        STAGE_A(kt1, 0, sb);
        asm volatile("s_waitcnt vmcnt(6)" ::: "memory");
        __builtin_amdgcn_s_barrier();
        __builtin_amdgcn_sched_barrier(0);
        bL[0] = RD_B(0, 0, bo); bL[1] = RD_B(0, 1, bo);
        bL[2] = RD_B(1, 0, bo); bL[3] = RD_B(1, 1, bo);
#pragma unroll
        for (int mf = 0; mf < 4; ++mf) {
            af[mf][0] = RD_A(mf, 0, bo);
            af[mf][1] = RD_A(mf, 1, bo);
        }
        __builtin_amdgcn_s_setprio(1);
#pragma unroll
        for (int kk = 0; kk < 2; ++kk)
#pragma unroll
            for (int mf = 0; mf < 4; ++mf)
#pragma unroll
                for (int nf = 0; nf < 2; ++nf)
                    acc[mf][nf] = __builtin_amdgcn_mfma_f32_16x16x32_bf16(
                        af[mf][kk], bL[nf * 2 + kk], acc[mf][nf], 0, 0, 0);
        __builtin_amdgcn_s_setprio(0);

        // ===== phase 1: quadrant (mq0, nq1) =====
        STAGE_B(kt1, 0, sb);
        asm volatile("s_waitcnt vmcnt(6)" ::: "memory");
        __builtin_amdgcn_s_barrier();
        __builtin_amdgcn_sched_barrier(0);
        bH[0] = RD_B(2, 0, bo); bH[1] = RD_B(2, 1, bo);
        bH[2] = RD_B(3, 0, bo); bH[3] = RD_B(3, 1, bo);
        __builtin_amdgcn_s_setprio(1);
#pragma unroll
        for (int kk = 0; kk < 2; ++kk)
#pragma unroll
            for (int mf = 0; mf < 4; ++mf)
#pragma unroll
                for (int nf = 0; nf < 2; ++nf)
                    acc[mf][2 + nf] = __builtin_amdgcn_mfma_f32_16x16x32_bf16(
                        af[mf][kk], bH[nf * 2 + kk], acc[mf][2 + nf], 0, 0, 0);
        __builtin_amdgcn_s_setprio(0);

        // ===== phase 2: quadrant (mq1, nq0) =====
        STAGE_B(kt1, 1, sb);
        asm volatile("s_waitcnt vmcnt(6)" ::: "memory");
        __builtin_amdgcn_s_barrier();
        __builtin_amdgcn_sched_barrier(0);
#pragma unroll
        for (int mf = 0; mf < 4; ++mf) {
            af[mf][0] = RD_A(4 + mf, 0, bo);
            af[mf][1] = RD_A(4 + mf, 1, bo);
        }
        __builtin_amdgcn_s_setprio(1);
#pragma unroll
        for (int kk = 0; kk < 2; ++kk)
#pragma unroll
            for (int mf = 0; mf < 4; ++mf)
#pragma unroll
                for (int nf = 0; nf < 2; ++nf)
                    acc[4 + mf][nf] = __builtin_amdgcn_mfma_f32_16x16x32_bf16(
                        af[mf][kk], bL[nf * 2 + kk], acc[4 + mf][nf], 0, 0, 0);
        __builtin_amdgcn_s_setprio(0);

        // ===== phase 3: quadrant (mq1, nq1) — zero ds_reads =====
        STAGE_A(kt1, 1, sb);
        asm volatile("s_waitcnt vmcnt(6)" ::: "memory");
        __builtin_amdgcn_s_barrier();
        __builtin_amdgcn_sched_barrier(0);
        __builtin_amdgcn_s_setprio(1);
#pragma unroll
        for (int kk = 0; kk < 2; ++kk)
#pragma unroll
            for (int mf = 0; mf < 4; ++mf)
#pragma unroll
                for (int nf = 0; nf < 2; ++nf)
                    acc[4 + mf][2 + nf] = __builtin_amdgcn_mfma_f32_16x16x32_bf16(
                        af[mf][kk], bH[nf * 2 + kk], acc[4 + mf][2 + nf], 0, 0, 0);
        __builtin_amdgcn_s_setprio(0);
    }

    // ---- epilogue: C/D layout col=lane&15, row=(lane>>4)*4+j ----
    const int crow = m0 + wm * 128 + lh * 4;
    const int ccol = n0 + wn * 64 + lr;
#pragma unroll
    for (int m = 0; m < 8; ++m)
#pragma unroll
        for (int n = 0; n < 4; ++n) {
            float* o = Out + (size_t)(crow + m * 16) * OUT_DIM + (ccol + n * 16);
#pragma unroll
            for (int j = 0; j < 4; ++j)
                o[(size_t)j * OUT_DIM] = acc[m][n][j];
        }
}

// ---------------------------------------------------------------------------
extern "C" void kernel_launch(void* const* d_in, const int* in_sizes, int n_in,
                              void* d_out, int out_size, void* d_ws, size_t ws_size,
                              hipStream_t stream) {
    const float* x  = (const float*)d_in[0];   // [8192, 4096]
    const float* rm = (const float*)d_in[1];   // [4096, 2]
    const float* cm = (const float*)d_in[2];   // [4096, 2]
    const float* al = (const float*)d_in[3];   // [4096]
    float* out = (float*)d_out;                // [8192, 4096]

    __bf16* Wt = (__bf16*)d_ws;                                     // 32 MiB
    __bf16* Xb = (__bf16*)((char*)d_ws + (size_t)32 * 1024 * 1024); // 64 MiB

    convert_x_kernel<<<BATCH * IN_DIM / (256 * 8), 256, 0, stream>>>(x, Xb);

    dim3 g1(IN_DIM / (256 * 8), OUT_DIM);      // (2, 4096)
    build_wt_kernel<<<g1, 256, 0, stream>>>(rm, cm, al, Wt);

    dim3 g2((BATCH / BM) * (OUT_DIM / BN));    // 512
    gemm_kernel<<<g2, THREADS, 0, stream>>>(Xb, Wt, out);
}

// Round 6
// 267.464 us; speedup vs baseline: 1.2849x; 1.0056x over previous
//
#include <hip/hip_runtime.h>
#include <hip/hip_bf16.h>
#include <cstdint>
#include <cstddef>

// out[B,OUT] = (x * alpha) @ W,  W[i,o] = exp(-||col_i - row_o||^2)
// B=8192, IN=4096, OUT=4096.  f32 in/out.
//
// k0 (fused prep): x f32 -> bf16 Xb ; Wt[o][i] = alpha[i]*exp(-d2) bf16 (B^T)
// k1: 256x256 GEMM, BK=64, 8 waves (2M x 4N), 4 quadrant-phases/K-tile.
//
// Register-pipelined phase schedule (reads prefetch NEXT phase's fragments, so
// the MFMA cluster of phase p consumes regs loaded in p-1 while p's reads issue
// underneath it -- removes the per-phase read-drain stall that capped r5 at 53%):
//   p0: stage A0+B0(t+1); vmcnt(6)[confirm B1(t)]; bar; read bH(t);  MFMA afL*bL
//   p1: stage B1(t+1);    vmcnt(6)[confirm A1(t)]; bar; read afH(t); MFMA afL*bH
//   p2: stage A1(t+1);    (no wait, no barrier);                     MFMA afH*bL
//   p3: vmcnt(4)[confirm A0B0(t+1)]; bar; read afL,bL(t+1) from buf^1; MFMA afH*bH
// RAW: every unit's confirm(vmcnt)+barrier strictly precedes its first ds_read
//   (A0B0: staged p0(t), confirmed p3(t), read p3(t); B1: p1(t)->p0(t+1);
//    A1: p2(t)->p1(t+1)); 3-phase stage->confirm distance covers HBM latency.
// WAR: each LDS region's last ds_read is >=3 barriers before its overwrite.
// In-flight floor 4 (never drains).  Reg liveness: afL dead after p1 -> refill
// p3; bL dead after p2 -> refill p3; bH/afH refilled p0/p1 of next tile.
// LDS row perm: A rho = mq*128+wm*64+(m&3)*16+lr, B rho = nq*128+wn*32+...;
// 16B chunk kc of row rho stored at kc ^ (rho&7); staging pre-swizzles the
// per-lane GLOBAL address (LDS dest linear per gload_lds rules); fragment
// reads conflict-free (measured 0).

#define IN_DIM  4096
#define OUT_DIM 4096
#define BATCH   8192

#define BM 256
#define BN 256
#define BK 64
#define KTILES (IN_DIM / BK)   // 64
#define THREADS 512

#define UNIT   8192            // elems per stage unit (128 rows * 64)
#define OPOFF  16384           // A (2 units) -> B offset
#define BUFOFF 32768           // elems per buffer (A + B)

#define NCONV  (BATCH * IN_DIM / (256 * 8))   // 16384 convert blocks
#define NWTB   (OUT_DIM * 2)                  // 8192 wt blocks

typedef __bf16 bf16x8 __attribute__((ext_vector_type(8)));
typedef float  f32x4  __attribute__((ext_vector_type(4)));

// ---------------------------------------------------------------------------
// Fused prep: blocks [0,NCONV) convert x; blocks [NCONV, NCONV+NWTB) build Wt.
// ---------------------------------------------------------------------------
__global__ __launch_bounds__(256) void prep_kernel(
    const float* __restrict__ x,
    const float* __restrict__ rows_mean,     // [OUT,2]
    const float* __restrict__ columns_mean,  // [IN,2]
    const float* __restrict__ alpha,         // [IN]
    __bf16* __restrict__ xb,                 // [BATCH][IN]
    __bf16* __restrict__ Wt)                 // [OUT][IN]
{
    const int b = blockIdx.x;
    if (b < NCONV) {
        const size_t i = ((size_t)b * 256 + threadIdx.x) * 8;
        const float4 v0 = *(const float4*)(x + i);
        const float4 v1 = *(const float4*)(x + i + 4);
        bf16x8 o;
        o[0] = (__bf16)v0.x; o[1] = (__bf16)v0.y; o[2] = (__bf16)v0.z; o[3] = (__bf16)v0.w;
        o[4] = (__bf16)v1.x; o[5] = (__bf16)v1.y; o[6] = (__bf16)v1.z; o[7] = (__bf16)v1.w;
        *(bf16x8*)(xb + i) = o;
    } else {
        const int bb = b - NCONV;
        const int o  = bb >> 1;
        const int i0 = ((bb & 1) * 256 + threadIdx.x) * 8;

        const float r0 = rows_mean[2 * o];
        const float r1 = rows_mean[2 * o + 1];

        const float4* cm = (const float4*)(columns_mean + 2 * (size_t)i0);
        float4 c01 = cm[0], c23 = cm[1], c45 = cm[2], c67 = cm[3];
        const float4* ap = (const float4*)(alpha + i0);
        float4 a0 = ap[0], a1 = ap[1];

        float cx[8] = {c01.x, c01.z, c23.x, c23.z, c45.x, c45.z, c67.x, c67.z};
        float cy[8] = {c01.y, c01.w, c23.y, c23.w, c45.y, c45.w, c67.y, c67.w};
        float av[8] = {a0.x, a0.y, a0.z, a0.w, a1.x, a1.y, a1.z, a1.w};

        bf16x8 w;
#pragma unroll
        for (int j = 0; j < 8; ++j) {
            float d0 = cx[j] - r0;
            float d1 = cy[j] - r1;
            w[j] = (__bf16)(__expf(-(d0 * d0 + d1 * d1)) * av[j]);
        }
        *(bf16x8*)(Wt + (size_t)o * IN_DIM + i0) = w;
    }
}

// ---------------------------------------------------------------------------
__global__ __launch_bounds__(THREADS, 2) void gemm_kernel(
    const __bf16* __restrict__ Xb,   // [BATCH, IN] bf16
    const __bf16* __restrict__ Wt,   // [OUT][IN]   bf16 (B^T)
    float* __restrict__ Out)         // [BATCH, OUT]
{
    __shared__ __align__(16) __bf16 lds[2 * BUFOFF];   // 128 KiB

    const int tid  = threadIdx.x;
    const int wave = tid >> 6;
    const int lane = tid & 63;
    const int lh   = lane >> 4;          // 0..3
    const int lr   = lane & 15;
    const int wm   = wave >> 2;          // 0..1  (M waves)
    const int wn   = wave & 3;           // 0..3  (N waves)

    // ---- XCD-aware block swizzle (512 wg, 512%8==0) ----
    const int swz  = (blockIdx.x & 7) * 64 + (blockIdx.x >> 3);
    const int m0   = (swz >> 4) * BM;
    const int n0   = (swz & 15) * BN;

    // ---- staging precompute (2 loads/thread per unit) ----
    const __bf16 *pA[2], *pB[2];
    __bf16 *lA[2], *lB[2];
#pragma unroll
    for (int j = 0; j < 2; ++j) {
        const int c  = wave * 64 + lane + j * 512;
        const int rp = c >> 3;
        const int kg = (c & 7) ^ (rp & 7);
        const int rA = ((rp >> 6) & 1) * 128 + (rp & 63);
        const int rB = (rp >> 5) * 64 + (rp & 31);
        pA[j] = Xb + (size_t)(m0 + rA) * IN_DIM + kg * 8;
        pB[j] = Wt + (size_t)(n0 + rB) * IN_DIM + kg * 8;
        lA[j] = lds + j * 4096 + wave * 512;          // wave-uniform dest
        lB[j] = lds + OPOFF + j * 4096 + wave * 512;
    }

    auto STAGE_A = [&](int kt, int h, int b) {
#pragma unroll
        for (int j = 0; j < 2; ++j)
            __builtin_amdgcn_global_load_lds(
                (const __attribute__((address_space(1))) unsigned int*)
                    (pA[j] + (size_t)h * 64 * IN_DIM + kt * BK),
                (__attribute__((address_space(3))) unsigned int*)
                    (lA[j] + b * BUFOFF + h * UNIT), 16, 0, 0);
    };
    auto STAGE_B = [&](int kt, int h, int b) {
#pragma unroll
        for (int j = 0; j < 2; ++j)
            __builtin_amdgcn_global_load_lds(
                (const __attribute__((address_space(1))) unsigned int*)
                    (pB[j] + (size_t)h * 32 * IN_DIM + kt * BK),
                (__attribute__((address_space(3))) unsigned int*)
                    (lB[j] + b * BUFOFF + h * UNIT), 16, 0, 0);
    };

    // ---- fragment read bases (swizzled chunks; rho&7 == lr&7) ----
    const int l7  = lr & 7;
    const int sc0 = lh ^ l7;          // kk=0 chunk
    const int sc1 = (4 + lh) ^ l7;    // kk=1 chunk
    const __bf16* aB = lds + (wm * 64 + lr) * 64;
    const __bf16* bB = lds + OPOFF + (wn * 32 + lr) * 64;

    auto RD_A = [&](int m, int kk, int bo) -> bf16x8 {
        return *(const bf16x8*)(aB + bo + (m >> 2) * UNIT + (m & 3) * 1024
                                + (kk ? sc1 : sc0) * 8);
    };
    auto RD_B = [&](int n, int kk, int bo) -> bf16x8 {
        return *(const bf16x8*)(bB + bo + (n >> 1) * UNIT + (n & 1) * 1024
                                + (kk ? sc1 : sc0) * 8);
    };

    f32x4 acc[8][4];
#pragma unroll
    for (int m = 0; m < 8; ++m)
#pragma unroll
        for (int n = 0; n < 4; ++n)
            acc[m][n] = f32x4{0.f, 0.f, 0.f, 0.f};

    // ---- prologue: tile 0 -> buf0; preload afL(0), bL(0) ----
    STAGE_A(0, 0, 0); STAGE_B(0, 0, 0); STAGE_B(0, 1, 0); STAGE_A(0, 1, 0);
    asm volatile("s_waitcnt vmcnt(0)" ::: "memory");
    __builtin_amdgcn_s_barrier();
    __builtin_amdgcn_sched_barrier(0);

    bf16x8 afL[4][2], afH[4][2], bL[4], bH[4];
#pragma unroll
    for (int mf = 0; mf < 4; ++mf) {
        afL[mf][0] = RD_A(mf, 0, 0);
        afL[mf][1] = RD_A(mf, 1, 0);
    }
    bL[0] = RD_B(0, 0, 0); bL[1] = RD_B(0, 1, 0);
    bL[2] = RD_B(1, 0, 0); bL[3] = RD_B(1, 1, 0);

    for (int t = 0; t < KTILES; ++t) {
        const int bo  = (t & 1) * BUFOFF;
        const int bo1 = BUFOFF - bo;
        const int sb  = (t & 1) ^ 1;
        const int kt1 = (t + 1 < KTILES) ? t + 1 : KTILES - 1;  // clamp benign

        // ===== phase 0: MFMA afL x bL  | prefetch bH(t) | stage A0+B0(t+1) =====
        STAGE_A(kt1, 0, sb);
        STAGE_B(kt1, 0, sb);
        asm volatile("s_waitcnt vmcnt(6)" ::: "memory");   // confirm B1(t)
        __builtin_amdgcn_s_barrier();
        __builtin_amdgcn_sched_barrier(0);
        bH[0] = RD_B(2, 0, bo); bH[1] = RD_B(2, 1, bo);
        bH[2] = RD_B(3, 0, bo); bH[3] = RD_B(3, 1, bo);
        __builtin_amdgcn_s_setprio(1);
#pragma unroll
        for (int kk = 0; kk < 2; ++kk)
#pragma unroll
            for (int mf = 0; mf < 4; ++mf)
#pragma unroll
                for (int nf = 0; nf < 2; ++nf)
                    acc[mf][nf] = __builtin_amdgcn_mfma_f32_16x16x32_bf16(
                        afL[mf][kk], bL[nf * 2 + kk], acc[mf][nf], 0, 0, 0);
        __builtin_amdgcn_s_setprio(0);

        // ===== phase 1: MFMA afL x bH  | prefetch afH(t) | stage B1(t+1) =====
        STAGE_B(kt1, 1, sb);
        asm volatile("s_waitcnt vmcnt(6)" ::: "memory");   // confirm A1(t)
        __builtin_amdgcn_s_barrier();
        __builtin_amdgcn_sched_barrier(0);
#pragma unroll
        for (int mf = 0; mf < 4; ++mf) {
            afH[mf][0] = RD_A(4 + mf, 0, bo);
            afH[mf][1] = RD_A(4 + mf, 1, bo);
        }
        __builtin_amdgcn_s_setprio(1);
#pragma unroll
        for (int kk = 0; kk < 2; ++kk)
#pragma unroll
            for (int mf = 0; mf < 4; ++mf)
#pragma unroll
                for (int nf = 0; nf < 2; ++nf)
                    acc[mf][2 + nf] = __builtin_amdgcn_mfma_f32_16x16x32_bf16(
                        afL[mf][kk], bH[nf * 2 + kk], acc[mf][2 + nf], 0, 0, 0);
        __builtin_amdgcn_s_setprio(0);

        // ===== phase 2: MFMA afH x bL  | stage A1(t+1) | no wait/barrier =====
        STAGE_A(kt1, 1, sb);
        __builtin_amdgcn_s_setprio(1);
#pragma unroll
        for (int kk = 0; kk < 2; ++kk)
#pragma unroll
            for (int mf = 0; mf < 4; ++mf)
#pragma unroll
                for (int nf = 0; nf < 2; ++nf)
                    acc[4 + mf][nf] = __builtin_amdgcn_mfma_f32_16x16x32_bf16(
                        afH[mf][kk], bL[nf * 2 + kk], acc[4 + mf][nf], 0, 0, 0);
        __builtin_amdgcn_s_setprio(0);

        // ===== phase 3: MFMA afH x bH | prefetch afL,bL(t+1) from buf^1 =====
        asm volatile("s_waitcnt vmcnt(4)" ::: "memory");   // confirm A0+B0(t+1)
        __builtin_amdgcn_s_barrier();
        __builtin_amdgcn_sched_barrier(0);
#pragma unroll
        for (int mf = 0; mf < 4; ++mf) {
            afL[mf][0] = RD_A(mf, 0, bo1);
            afL[mf][1] = RD_A(mf, 1, bo1);
        }
        bL[0] = RD_B(0, 0, bo1); bL[1] = RD_B(0, 1, bo1);
        bL[2] = RD_B(1, 0, bo1); bL[3] = RD_B(1, 1, bo1);
        __builtin_amdgcn_s_setprio(1);
#pragma unroll
        for (int kk = 0; kk < 2; ++kk)
#pragma unroll
            for (int mf = 0; mf < 4; ++mf)
#pragma unroll
                for (int nf = 0; nf < 2; ++nf)
                    acc[4 + mf][2 + nf] = __builtin_amdgcn_mfma_f32_16x16x32_bf16(
                        afH[mf][kk], bH[nf * 2 + kk], acc[4 + mf][2 + nf], 0, 0, 0);
        __builtin_amdgcn_s_setprio(0);
    }

    // ---- epilogue: C/D layout col=lane&15, row=(lane>>4)*4+j ----
    const int crow = m0 + wm * 128 + lh * 4;
    const int ccol = n0 + wn * 64 + lr;
#pragma unroll
    for (int m = 0; m < 8; ++m)
#pragma unroll
        for (int n = 0; n < 4; ++n) {
            float* o = Out + (size_t)(crow + m * 16) * OUT_DIM + (ccol + n * 16);
#pragma unroll
            for (int j = 0; j < 4; ++j)
                o[(size_t)j * OUT_DIM] = acc[m][n][j];
        }
}

// ---------------------------------------------------------------------------
extern "C" void kernel_launch(void* const* d_in, const int* in_sizes, int n_in,
                              void* d_out, int out_size, void* d_ws, size_t ws_size,
                              hipStream_t stream) {
    const float* x  = (const float*)d_in[0];   // [8192, 4096]
    const float* rm = (const float*)d_in[1];   // [4096, 2]
    const float* cm = (const float*)d_in[2];   // [4096, 2]
    const float* al = (const float*)d_in[3];   // [4096]
    float* out = (float*)d_out;                // [8192, 4096]

    __bf16* Wt = (__bf16*)d_ws;                                     // 32 MiB
    __bf16* Xb = (__bf16*)((char*)d_ws + (size_t)32 * 1024 * 1024); // 64 MiB

    prep_kernel<<<NCONV + NWTB, 256, 0, stream>>>(x, rm, cm, al, Xb, Wt);

    dim3 g2((BATCH / BM) * (OUT_DIM / BN));    // 512
    gemm_kernel<<<g2, THREADS, 0, stream>>>(Xb, Wt, out);
}